// Round 5
// baseline (127.052 us; speedup 1.0000x reference)
//
#include <hip/hip_runtime.h>
#include <hip/hip_bf16.h>
#include <hip/hip_fp16.h>

// NAM_89739046683406: per-feature tiny MLP (B=32768, F=128, H=64)
// logit(b) = bias + sum_f [ relu(relu(x[b,f]*w1[f]+b1[f]) @ w2[f] + b2[f]) . w3[f] + b3[f] ]
// out = [1-sigmoid, sigmoid]
//
// R26 = R22 body (best: 52.1us main) with __launch_bounds__(256) -- max
// threads only, NO min-waves clause. Rationale: real duty cycles are VALU
// ~21%, MFMA ~8%, HBM 5% -> latency-bound at 3 waves/SIMD. R24 proved
// LB(256,4) makes the RA panic-demote to 64 VGPR + spill; but the HW
// occupancy rule is waves/SIMD = 8/4/2 at <=64/<=128/<=256 VGPR, so a FREE
// allocation landing at ~84-100 VGPR gives 4 waves/SIMD at runtime with no
// allocator coercion. 2048 blocks / 256 CU / 4 resident = exactly 2 rounds.
//
// Evidence ledger:
//   - x-path exonerated twice: R23 (per-lane gathers) and R25 (LDS staging)
//     both failed to beat the shfl broadcast. Keep R22's chunk body.
//   - LB(256,4) demotes (R24: VGPR->64, FETCH 25MB/WRITE 37MB, 52->71us).
//   - NO float-ext-vector arrays + __builtin_elementwise_* (R17/R18).
//   - Judge spills by FETCH/WRITE counters, not VGPR_Count.
// Failure signatures for THIS round:
//   (A) VGPR 64 + FETCH/WRITE blowup -> LB(256,3) is final; go pipeline route.
//   (B) VGPR >128 -> 2 waves/SIMD, main ~70us -> same revert.

#define B_SZ 32768
#define F_SZ 128
#define H_SZ 64

typedef _Float16 half8 __attribute__((ext_vector_type(8)));  // f16 x8 (4 VGPR)
typedef float floatx4 __attribute__((ext_vector_type(4)));   // fp32 x4 acc

union U8 { half8 v; unsigned u[4]; };

// pack two fp32 -> half2 bits (RNE)
__device__ __forceinline__ unsigned pkh(float lo, float hi) {
    __half2 h = __float22half2_rn(make_float2(lo, hi));
    return __builtin_bit_cast(unsigned, h);
}

// packed f16 relu via v_pk_max_f16
__device__ __forceinline__ unsigned relu2(unsigned a) {
    unsigned r;
    asm("v_pk_max_f16 %0, %1, %2" : "=v"(r) : "v"(a), "v"(0u));
    return r;
}

__device__ __forceinline__ __half2 bch2(unsigned u) {
    return __builtin_bit_cast(__half2, u);
}

// ---- main: block = 4 waves; wave wv owns feature f = (bx>>6)*4+wv,
//      rows [rg*512, rg*512+512), rg = bx&63. 8 chunks of 64 rows.
//      Preamble packs w2[f] -> f16 A-fragments in registers.
//      Output: part[gf][rb..rb+512) plain store (sole writer).
__global__ __launch_bounds__(256)
void nam_main(const float* __restrict__ x,
              const float* __restrict__ w1, const float* __restrict__ b1,
              const float* __restrict__ b2, const float* __restrict__ w3,
              const float* __restrict__ b3,
              const float* __restrict__ w2,
              float* __restrict__ part)
{
    __shared__ float partial[4][512];    // 8KB

    const int tid  = threadIdx.x;
    const int lane = tid & 63;
    const int wv   = tid >> 6;           // 0..3
    const int l15  = lane & 15;
    const int quad = lane >> 4;
    const int rg   = blockIdx.x & 63;
    const int gf   = blockIdx.x >> 6;    // 0..31
    const int f    = gf * 4 + wv;
    const int rb   = rg * 512;

    // ---- per-wave resident tables ----
    // w2 A-fragments packed in-place from fp32 source (f16):
    // frag (gt,ks): elem j = w2[f][k=ks*32+quad*8+j][g=gt*16+l15]
    const float* w2f = w2 + (size_t)f * H_SZ * H_SZ;
    half8 wfrag[4][2];
    #pragma unroll
    for (int gt = 0; gt < 4; ++gt)
        #pragma unroll
        for (int ks = 0; ks < 2; ++ks) {
            const float* src = w2f + (ks * 32 + quad * 8) * H_SZ + gt * 16 + l15;
            U8 o;
            #pragma unroll
            for (int t = 0; t < 4; ++t)
                o.u[t] = pkh(src[(2 * t) * H_SZ], src[(2 * t + 1) * H_SZ]);
            wfrag[gt][ks] = o.v;
        }

    // w1/b1 as packed half2: element k = ks*32 + quad*8 + (2t, 2t+1)
    unsigned wk2[2][4], bk2[2][4];
    #pragma unroll
    for (int ks = 0; ks < 2; ++ks) {
        float wtmp[8], btmp[8];
        const float4* wq = (const float4*)(w1 + f * 64 + ks * 32 + quad * 8);
        const float4* bq = (const float4*)(b1 + f * 64 + ks * 32 + quad * 8);
        *(float4*)&wtmp[0] = wq[0]; *(float4*)&wtmp[4] = wq[1];
        *(float4*)&btmp[0] = bq[0]; *(float4*)&btmp[4] = bq[1];
        #pragma unroll
        for (int t = 0; t < 4; ++t) {
            wk2[ks][t] = pkh(wtmp[2 * t], wtmp[2 * t + 1]);
            bk2[ks][t] = pkh(btmp[2 * t], btmp[2 * t + 1]);
        }
    }

    // b2 as MFMA C operand quads; w3 scalar: element g = gt*16 + quad*4 + i
    floatx4 b2c[4];
    float w3f[4][4];
    #pragma unroll
    for (int gt = 0; gt < 4; ++gt) {
        float4 bv  = *(const float4*)(b2 + f * 64 + gt * 16 + quad * 4);
        float4 wv3 = *(const float4*)(w3 + f * 64 + gt * 16 + quad * 4);
        b2c[gt] = floatx4{bv.x, bv.y, bv.z, bv.w};
        w3f[gt][0] = wv3.x; w3f[gt][1] = wv3.y;
        w3f[gt][2] = wv3.z; w3f[gt][3] = wv3.w;
    }
    const float b3f = b3[f];

    // ---- 8 chunks of 64 rows, software-pipelined x gather ----
    float xv = x[(size_t)(rb + lane) * F_SZ + f];   // chunk 0

    #pragma unroll 1
    for (int c = 0; c < 8; ++c) {
        float xvn;
        if (c < 7)
            xvn = x[(size_t)(rb + (c + 1) * 64 + lane) * F_SZ + f];

        // splat-pack x to half2 once, broadcast packed word per 16-row block
        unsigned xpk = __builtin_bit_cast(unsigned, __float2half2_rn(xv));
        unsigned xf[4];
        #pragma unroll
        for (int bt = 0; bt < 4; ++bt)
            xf[bt] = (unsigned)__shfl((int)xpk, bt * 16 + l15, 64);

        // h1 B-fragments in packed f16: B[k=quad*8+j][n=bt*16+l15]
        // per pair: 1 v_pk_fma_f16 + 1 v_pk_max_f16, result is the frag word
        half8 hfrag[4][2];
        #pragma unroll
        for (int ks = 0; ks < 2; ++ks)
            #pragma unroll
            for (int bt = 0; bt < 4; ++bt) {
                U8 o;
                #pragma unroll
                for (int t = 0; t < 4; ++t) {
                    __half2 h = __hfma2(bch2(xf[bt]), bch2(wk2[ks][t]), bch2(bk2[ks][t]));
                    o.u[t] = relu2(__builtin_bit_cast(unsigned, h));
                }
                hfrag[bt][ks] = o.v;
            }

        // MFMA f16 (C = b2c direct, D != C) + epilogue
        // D layout: g = gt*16 + quad*4 + i, n = bt*16 + l15
        float t[4] = {0.0f, 0.0f, 0.0f, 0.0f};
        #pragma unroll
        for (int gt = 0; gt < 4; ++gt)
            #pragma unroll
            for (int bt = 0; bt < 4; ++bt) {
                floatx4 acc = __builtin_amdgcn_mfma_f32_16x16x32_f16(
                    wfrag[gt][0], hfrag[bt][0], b2c[gt], 0, 0, 0);
                acc = __builtin_amdgcn_mfma_f32_16x16x32_f16(
                    wfrag[gt][1], hfrag[bt][1], acc, 0, 0, 0);
                #pragma unroll
                for (int i = 0; i < 4; ++i)
                    t[bt] = fmaf(fmaxf(acc[i], 0.0f), w3f[gt][i], t[bt]);
            }

        // quad-reduce (row = bt*16 + l15), publish per-chunk rows
        #pragma unroll
        for (int bt = 0; bt < 4; ++bt) {
            t[bt] += __shfl_xor(t[bt], 16, 64);
            t[bt] += __shfl_xor(t[bt], 32, 64);
        }
        if (quad == 0) {
            #pragma unroll
            for (int bt = 0; bt < 4; ++bt)
                partial[wv][c * 64 + bt * 16 + l15] = t[bt] + b3f;
        }

        xv = xvn;
    }

    __syncthreads();

    // block reduce over the 4 features -> plain coalesced store (sole writer)
    #pragma unroll
    for (int k = 0; k < 2; ++k) {
        int row = k * 256 + tid;
        float p = partial[0][row] + partial[1][row]
                + partial[2][row] + partial[3][row];
        part[(size_t)gf * B_SZ + rb + row] = p;
    }
}

// ---- final: 1 row/thread, sum 32 gf-partials + bias + sigmoid ----
__global__ __launch_bounds__(256)
void nam_final(const float* __restrict__ part, const float* __restrict__ bias,
               float* __restrict__ out)
{
    int b = blockIdx.x * 256 + threadIdx.x;
    float s = bias[0];
    #pragma unroll
    for (int gf = 0; gf < 32; ++gf)
        s += part[(size_t)gf * B_SZ + b];
    float p = 1.0f / (1.0f + __expf(-s));
    ((float2*)out)[b] = make_float2(1.0f - p, p);
}

extern "C" void kernel_launch(void* const* d_in, const int* in_sizes, int n_in,
                              void* d_out, int out_size, void* d_ws, size_t ws_size,
                              hipStream_t stream)
{
    const float* x    = (const float*)d_in[0];
    const float* w1   = (const float*)d_in[1];
    const float* b1   = (const float*)d_in[2];
    const float* w2   = (const float*)d_in[3];
    const float* b2   = (const float*)d_in[4];
    const float* w3   = (const float*)d_in[5];
    const float* b3   = (const float*)d_in[6];
    const float* bias = (const float*)d_in[7];
    float* out = (float*)d_out;

    float* part = (float*)d_ws;   // part[32][B_SZ], 4MB

    nam_main<<<dim3(2048), dim3(256), 0, stream>>>(
        x, w1, b1, b2, w3, b3, w2, part);
    nam_final<<<dim3(B_SZ / 256), dim3(256), 0, stream>>>(part, bias, out);
}

// Round 6
// 123.907 us; speedup vs baseline: 1.0254x; 1.0254x over previous
//
#include <hip/hip_runtime.h>
#include <hip/hip_bf16.h>
#include <hip/hip_fp16.h>

// NAM_89739046683406: per-feature tiny MLP (B=32768, F=128, H=64)
// logit(b) = bias + sum_f [ relu(relu(x[b,f]*w1[f]+b1[f]) @ w2[f] + b2[f]) . w3[f] + b3[f] ]
// out = [1-sigmoid, sigmoid]
//
// R27 = R22 with the chunk loop restructured for latency, occupancy pinned
// at LB(256,3) (ledger below):
//   - chunk 64 -> 128 rows (4 chunks instead of 8): halves chunk-edge
//     serialization (broadcast waits, reduce tails, prefetch joins).
//   - per-bt build->consume: each of the 8 bt streams builds its 2 h1
//     fragments, immediately runs its 8 MFMAs + epilogue, fragments die.
//     hfrag liveness 32->~16 VGPR; 8 independent streams/chunk let bt+1's
//     VALU build cover bt's MFMA latency.
//   - epilogue dep-depth cut: per-gt accumulators, pairwise sum (16->~6).
// Rationale: wall-clock shows ~5.9k cyc/chunk vs ~650 issue-cyc of work ->
// ~85% dependency-stall at 2-3 waves/SIMD. x-path exonerated (R23/R25).
//
// Occupancy ledger (FINAL): LB(256,3)=26% best; LB(256,4) spills (R24:
// VGPR->64, FETCH 25MB/WRITE 37MB, 71us); LB(256) under-resides (R26:
// occ 18.5%, 62us). VGPR budget under (256,3) is ~168.
// Other constraints: NO float-ext-vector arrays + __builtin_elementwise_*
// (R17/R18); judge spills by FETCH/WRITE, not VGPR_Count.
// Failure signature THIS round: FETCH>20MB or WRITE>8MB = spill from the
// 128-row chunk -> keep per-bt restructure, revert chunk to 64.

#define B_SZ 32768
#define F_SZ 128
#define H_SZ 64

typedef _Float16 half8 __attribute__((ext_vector_type(8)));  // f16 x8 (4 VGPR)
typedef float floatx4 __attribute__((ext_vector_type(4)));   // fp32 x4 acc

union U8 { half8 v; unsigned u[4]; };

// pack two fp32 -> half2 bits (RNE)
__device__ __forceinline__ unsigned pkh(float lo, float hi) {
    __half2 h = __float22half2_rn(make_float2(lo, hi));
    return __builtin_bit_cast(unsigned, h);
}

// packed f16 relu via v_pk_max_f16
__device__ __forceinline__ unsigned relu2(unsigned a) {
    unsigned r;
    asm("v_pk_max_f16 %0, %1, %2" : "=v"(r) : "v"(a), "v"(0u));
    return r;
}

__device__ __forceinline__ __half2 bch2(unsigned u) {
    return __builtin_bit_cast(__half2, u);
}

// ---- main: block = 4 waves; wave wv owns feature f = (bx>>6)*4+wv,
//      rows [rg*512, rg*512+512), rg = bx&63. 4 chunks of 128 rows.
//      Preamble packs w2[f] -> f16 A-fragments in registers.
//      Output: part[gf][rb..rb+512) plain store (sole writer).
__global__ __launch_bounds__(256, 3)
void nam_main(const float* __restrict__ x,
              const float* __restrict__ w1, const float* __restrict__ b1,
              const float* __restrict__ b2, const float* __restrict__ w3,
              const float* __restrict__ b3,
              const float* __restrict__ w2,
              float* __restrict__ part)
{
    __shared__ float partial[4][512];    // 8KB

    const int tid  = threadIdx.x;
    const int lane = tid & 63;
    const int wv   = tid >> 6;           // 0..3
    const int l15  = lane & 15;
    const int quad = lane >> 4;
    const int rg   = blockIdx.x & 63;
    const int gf   = blockIdx.x >> 6;    // 0..31
    const int f    = gf * 4 + wv;
    const int rb   = rg * 512;

    // ---- per-wave resident tables ----
    // w2 A-fragments packed in-place from fp32 source (f16):
    // frag (gt,ks): elem j = w2[f][k=ks*32+quad*8+j][g=gt*16+l15]
    const float* w2f = w2 + (size_t)f * H_SZ * H_SZ;
    half8 wfrag[4][2];
    #pragma unroll
    for (int gt = 0; gt < 4; ++gt)
        #pragma unroll
        for (int ks = 0; ks < 2; ++ks) {
            const float* src = w2f + (ks * 32 + quad * 8) * H_SZ + gt * 16 + l15;
            U8 o;
            #pragma unroll
            for (int t = 0; t < 4; ++t)
                o.u[t] = pkh(src[(2 * t) * H_SZ], src[(2 * t + 1) * H_SZ]);
            wfrag[gt][ks] = o.v;
        }

    // w1/b1 as packed half2: element k = ks*32 + quad*8 + (2t, 2t+1)
    unsigned wk2[2][4], bk2[2][4];
    #pragma unroll
    for (int ks = 0; ks < 2; ++ks) {
        float wtmp[8], btmp[8];
        const float4* wq = (const float4*)(w1 + f * 64 + ks * 32 + quad * 8);
        const float4* bq = (const float4*)(b1 + f * 64 + ks * 32 + quad * 8);
        *(float4*)&wtmp[0] = wq[0]; *(float4*)&wtmp[4] = wq[1];
        *(float4*)&btmp[0] = bq[0]; *(float4*)&btmp[4] = bq[1];
        #pragma unroll
        for (int t = 0; t < 4; ++t) {
            wk2[ks][t] = pkh(wtmp[2 * t], wtmp[2 * t + 1]);
            bk2[ks][t] = pkh(btmp[2 * t], btmp[2 * t + 1]);
        }
    }

    // b2 as MFMA C operand quads; w3 scalar: element g = gt*16 + quad*4 + i
    floatx4 b2c[4];
    float w3f[4][4];
    #pragma unroll
    for (int gt = 0; gt < 4; ++gt) {
        float4 bv  = *(const float4*)(b2 + f * 64 + gt * 16 + quad * 4);
        float4 wv3 = *(const float4*)(w3 + f * 64 + gt * 16 + quad * 4);
        b2c[gt] = floatx4{bv.x, bv.y, bv.z, bv.w};
        w3f[gt][0] = wv3.x; w3f[gt][1] = wv3.y;
        w3f[gt][2] = wv3.z; w3f[gt][3] = wv3.w;
    }
    const float b3f = b3[f];

    // ---- 4 chunks of 128 rows, software-pipelined x gather (2 loads/chunk)
    float xv0 = x[(size_t)(rb + lane) * F_SZ + f];
    float xv1 = x[(size_t)(rb + 64 + lane) * F_SZ + f];

    #pragma unroll 1
    for (int c = 0; c < 4; ++c) {
        float xn0, xn1;
        if (c < 3) {
            xn0 = x[(size_t)(rb + (c + 1) * 128 + lane) * F_SZ + f];
            xn1 = x[(size_t)(rb + (c + 1) * 128 + 64 + lane) * F_SZ + f];
        }

        // splat-pack both row-halves to half2 once
        const unsigned xpk0 = __builtin_bit_cast(unsigned, __float2half2_rn(xv0));
        const unsigned xpk1 = __builtin_bit_cast(unsigned, __float2half2_rn(xv1));

        // 8 independent bt streams: build 2 fragments -> 8 MFMA -> epilogue
        // -> reduce -> publish. Fragments die per-bt (low liveness); bt+1's
        // VALU build overlaps bt's MFMA latency.
        #pragma unroll
        for (int bt = 0; bt < 8; ++bt) {
            const unsigned xsrc = (bt < 4) ? xpk0 : xpk1;
            const unsigned xf = (unsigned)__shfl((int)xsrc, (bt & 3) * 16 + l15, 64);

            // h1 fragments: B[k=quad*8+j][n = bt*16+l15], ks = k-half
            half8 hf0, hf1;
            {
                U8 o0, o1;
                #pragma unroll
                for (int t = 0; t < 4; ++t) {
                    __half2 h0 = __hfma2(bch2(xf), bch2(wk2[0][t]), bch2(bk2[0][t]));
                    __half2 h1 = __hfma2(bch2(xf), bch2(wk2[1][t]), bch2(bk2[1][t]));
                    o0.u[t] = relu2(__builtin_bit_cast(unsigned, h0));
                    o1.u[t] = relu2(__builtin_bit_cast(unsigned, h1));
                }
                hf0 = o0.v; hf1 = o1.v;
            }

            // MFMA f16 (C = b2c direct, D != C) + epilogue
            // D layout: g = gt*16 + quad*4 + i
            float tg[4];
            #pragma unroll
            for (int gt = 0; gt < 4; ++gt) {
                floatx4 acc = __builtin_amdgcn_mfma_f32_16x16x32_f16(
                    wfrag[gt][0], hf0, b2c[gt], 0, 0, 0);
                acc = __builtin_amdgcn_mfma_f32_16x16x32_f16(
                    wfrag[gt][1], hf1, acc, 0, 0, 0);
                float s = 0.0f;
                #pragma unroll
                for (int i = 0; i < 4; ++i)
                    s = fmaf(fmaxf(acc[i], 0.0f), w3f[gt][i], s);
                tg[gt] = s;
            }
            float tb = (tg[0] + tg[1]) + (tg[2] + tg[3]);

            // quad-reduce (row = c*128 + bt*16 + l15), publish
            tb += __shfl_xor(tb, 16, 64);
            tb += __shfl_xor(tb, 32, 64);
            if (quad == 0)
                partial[wv][c * 128 + bt * 16 + l15] = tb + b3f;
        }

        xv0 = xn0; xv1 = xn1;
    }

    __syncthreads();

    // block reduce over the 4 features -> plain coalesced store (sole writer)
    #pragma unroll
    for (int k = 0; k < 2; ++k) {
        int row = k * 256 + tid;
        float p = partial[0][row] + partial[1][row]
                + partial[2][row] + partial[3][row];
        part[(size_t)gf * B_SZ + rb + row] = p;
    }
}

// ---- final: 1 row/thread, sum 32 gf-partials + bias + sigmoid ----
__global__ __launch_bounds__(256)
void nam_final(const float* __restrict__ part, const float* __restrict__ bias,
               float* __restrict__ out)
{
    int b = blockIdx.x * 256 + threadIdx.x;
    float s = bias[0];
    #pragma unroll
    for (int gf = 0; gf < 32; ++gf)
        s += part[(size_t)gf * B_SZ + b];
    float p = 1.0f / (1.0f + __expf(-s));
    ((float2*)out)[b] = make_float2(1.0f - p, p);
}

extern "C" void kernel_launch(void* const* d_in, const int* in_sizes, int n_in,
                              void* d_out, int out_size, void* d_ws, size_t ws_size,
                              hipStream_t stream)
{
    const float* x    = (const float*)d_in[0];
    const float* w1   = (const float*)d_in[1];
    const float* b1   = (const float*)d_in[2];
    const float* w2   = (const float*)d_in[3];
    const float* b2   = (const float*)d_in[4];
    const float* w3   = (const float*)d_in[5];
    const float* b3   = (const float*)d_in[6];
    const float* bias = (const float*)d_in[7];
    float* out = (float*)d_out;

    float* part = (float*)d_ws;   // part[32][B_SZ], 4MB

    nam_main<<<dim3(2048), dim3(256), 0, stream>>>(
        x, w1, b1, b2, w3, b3, w2, part);
    nam_final<<<dim3(B_SZ / 256), dim3(256), 0, stream>>>(part, bias, out);
}

// Round 7
// 119.275 us; speedup vs baseline: 1.0652x; 1.0388x over previous
//
#include <hip/hip_runtime.h>
#include <hip/hip_bf16.h>
#include <hip/hip_fp16.h>

// NAM_89739046683406: per-feature tiny MLP (B=32768, F=128, H=64)
// logit(b) = bias + sum_f [ relu(relu(x[b,f]*w1[f]+b1[f]) @ w2[f] + b2[f]) . w3[f] + b3[f] ]
// out = [1-sigmoid, sigmoid]
//
// R28 = R22 body with the chunk-tail reduce replaced by direct per-quad LDS
// scatter. Rationale: occupancy is non-monotonic and peaks at R22's config
// (R26 occ 18.5%->61.7us, R22 26%->52.4, R27 33.7%->56.7) -> resident waves
// are NOT the lever; x-path exonerated (R23/R25). The last unprobed serial
// chain in the chunk is the reduce tail: 8 shfl_xor (lgkm-waited, dep-2) +
// exec-mask for quad==0. Replace with unconditional ds_write_b32 of each
// lane's t[bt] into partial4[wv*4+quad][row], stride 520 floats = exactly
// 2 lanes/bank (free, m136). Cross-quad sum moves to the once-per-block
// final reduce (16 reads/row). b3 folded as b3f*0.25 per quad (exact scale).
//
// Evidence ledger:
//   - LB(256,3) FINAL: (256,4) spills (R24), plain (256) under-resides (R26).
//   - x-path exonerated twice (R23 gathers, R25 LDS staging).
//   - per-bt build->consume restructure loses (R27); keep batch build + MFMA.
//   - NO float-ext-vector arrays + __builtin_elementwise_* (R17/R18).
//   - Judge spills by FETCH/WRITE counters, not VGPR_Count.
// Failure read for THIS round: neutral result = chunk-tail wasn't critical
// either -> structure is mined out at this shape.

#define B_SZ 32768
#define F_SZ 128
#define H_SZ 64
#define P_STRIDE 520   // 512 + 8: quad offset 8 banks -> 2 lanes/bank (free)

typedef _Float16 half8 __attribute__((ext_vector_type(8)));  // f16 x8 (4 VGPR)
typedef float floatx4 __attribute__((ext_vector_type(4)));   // fp32 x4 acc

union U8 { half8 v; unsigned u[4]; };

// pack two fp32 -> half2 bits (RNE)
__device__ __forceinline__ unsigned pkh(float lo, float hi) {
    __half2 h = __float22half2_rn(make_float2(lo, hi));
    return __builtin_bit_cast(unsigned, h);
}

// packed f16 relu via v_pk_max_f16
__device__ __forceinline__ unsigned relu2(unsigned a) {
    unsigned r;
    asm("v_pk_max_f16 %0, %1, %2" : "=v"(r) : "v"(a), "v"(0u));
    return r;
}

__device__ __forceinline__ __half2 bch2(unsigned u) {
    return __builtin_bit_cast(__half2, u);
}

// ---- main: block = 4 waves; wave wv owns feature f = (bx>>6)*4+wv,
//      rows [rg*512, rg*512+512), rg = bx&63. 8 chunks of 64 rows.
//      Preamble packs w2[f] -> f16 A-fragments in registers.
//      Chunk loop: broadcast -> pk-build -> MFMA/epilogue -> 4 LDS stores.
//      Output: part[gf][rb..rb+512) plain store (sole writer).
__global__ __launch_bounds__(256, 3)
void nam_main(const float* __restrict__ x,
              const float* __restrict__ w1, const float* __restrict__ b1,
              const float* __restrict__ b2, const float* __restrict__ w3,
              const float* __restrict__ b3,
              const float* __restrict__ w2,
              float* __restrict__ part)
{
    __shared__ float partial4[16][P_STRIDE];   // 33.3KB, [wv*4+quad][row]

    const int tid  = threadIdx.x;
    const int lane = tid & 63;
    const int wv   = tid >> 6;           // 0..3
    const int l15  = lane & 15;
    const int quad = lane >> 4;
    const int rg   = blockIdx.x & 63;
    const int gf   = blockIdx.x >> 6;    // 0..31
    const int f    = gf * 4 + wv;
    const int rb   = rg * 512;

    // ---- per-wave resident tables ----
    // w2 A-fragments packed in-place from fp32 source (f16):
    // frag (gt,ks): elem j = w2[f][k=ks*32+quad*8+j][g=gt*16+l15]
    const float* w2f = w2 + (size_t)f * H_SZ * H_SZ;
    half8 wfrag[4][2];
    #pragma unroll
    for (int gt = 0; gt < 4; ++gt)
        #pragma unroll
        for (int ks = 0; ks < 2; ++ks) {
            const float* src = w2f + (ks * 32 + quad * 8) * H_SZ + gt * 16 + l15;
            U8 o;
            #pragma unroll
            for (int t = 0; t < 4; ++t)
                o.u[t] = pkh(src[(2 * t) * H_SZ], src[(2 * t + 1) * H_SZ]);
            wfrag[gt][ks] = o.v;
        }

    // w1/b1 as packed half2: element k = ks*32 + quad*8 + (2t, 2t+1)
    unsigned wk2[2][4], bk2[2][4];
    #pragma unroll
    for (int ks = 0; ks < 2; ++ks) {
        float wtmp[8], btmp[8];
        const float4* wq = (const float4*)(w1 + f * 64 + ks * 32 + quad * 8);
        const float4* bq = (const float4*)(b1 + f * 64 + ks * 32 + quad * 8);
        *(float4*)&wtmp[0] = wq[0]; *(float4*)&wtmp[4] = wq[1];
        *(float4*)&btmp[0] = bq[0]; *(float4*)&btmp[4] = bq[1];
        #pragma unroll
        for (int t = 0; t < 4; ++t) {
            wk2[ks][t] = pkh(wtmp[2 * t], wtmp[2 * t + 1]);
            bk2[ks][t] = pkh(btmp[2 * t], btmp[2 * t + 1]);
        }
    }

    // b2 as MFMA C operand quads; w3 scalar: element g = gt*16 + quad*4 + i
    floatx4 b2c[4];
    float w3f[4][4];
    #pragma unroll
    for (int gt = 0; gt < 4; ++gt) {
        float4 bv  = *(const float4*)(b2 + f * 64 + gt * 16 + quad * 4);
        float4 wv3 = *(const float4*)(w3 + f * 64 + gt * 16 + quad * 4);
        b2c[gt] = floatx4{bv.x, bv.y, bv.z, bv.w};
        w3f[gt][0] = wv3.x; w3f[gt][1] = wv3.y;
        w3f[gt][2] = wv3.z; w3f[gt][3] = wv3.w;
    }
    const float b3q = b3[f] * 0.25f;   // summed 4x across quads -> exact b3

    // per-lane LDS row base: partial4[wv*4+quad][l15 + ...]
    float* pbase = &partial4[wv * 4 + quad][l15];

    // ---- 8 chunks of 64 rows, software-pipelined x gather ----
    float xv = x[(size_t)(rb + lane) * F_SZ + f];   // chunk 0

    #pragma unroll 1
    for (int c = 0; c < 8; ++c) {
        float xvn;
        if (c < 7)
            xvn = x[(size_t)(rb + (c + 1) * 64 + lane) * F_SZ + f];

        // splat-pack x to half2 once, broadcast packed word per 16-row block
        unsigned xpk = __builtin_bit_cast(unsigned, __float2half2_rn(xv));
        unsigned xf[4];
        #pragma unroll
        for (int bt = 0; bt < 4; ++bt)
            xf[bt] = (unsigned)__shfl((int)xpk, bt * 16 + l15, 64);

        // h1 B-fragments in packed f16: B[k=quad*8+j][n=bt*16+l15]
        half8 hfrag[4][2];
        #pragma unroll
        for (int ks = 0; ks < 2; ++ks)
            #pragma unroll
            for (int bt = 0; bt < 4; ++bt) {
                U8 o;
                #pragma unroll
                for (int t = 0; t < 4; ++t) {
                    __half2 h = __hfma2(bch2(xf[bt]), bch2(wk2[ks][t]), bch2(bk2[ks][t]));
                    o.u[t] = relu2(__builtin_bit_cast(unsigned, h));
                }
                hfrag[bt][ks] = o.v;
            }

        // MFMA f16 (C = b2c direct, D != C) + epilogue
        // D layout: g = gt*16 + quad*4 + i, n = bt*16 + l15
        float t[4] = {0.0f, 0.0f, 0.0f, 0.0f};
        #pragma unroll
        for (int gt = 0; gt < 4; ++gt)
            #pragma unroll
            for (int bt = 0; bt < 4; ++bt) {
                floatx4 acc = __builtin_amdgcn_mfma_f32_16x16x32_f16(
                    wfrag[gt][0], hfrag[bt][0], b2c[gt], 0, 0, 0);
                acc = __builtin_amdgcn_mfma_f32_16x16x32_f16(
                    wfrag[gt][1], hfrag[bt][1], acc, 0, 0, 0);
                #pragma unroll
                for (int i = 0; i < 4; ++i)
                    t[bt] = fmaf(fmaxf(acc[i], 0.0f), w3f[gt][i], t[bt]);
            }

        // per-quad partial publish: no shuffles, no branch, fire-and-forget
        #pragma unroll
        for (int bt = 0; bt < 4; ++bt)
            pbase[c * 64 + bt * 16] = t[bt] + b3q;

        xv = xvn;
    }

    __syncthreads();

    // block reduce over 4 features x 4 quads -> coalesced store (sole writer)
    #pragma unroll
    for (int k = 0; k < 2; ++k) {
        int row = k * 256 + tid;
        float s0 = 0.0f, s1 = 0.0f, s2 = 0.0f, s3 = 0.0f;
        #pragma unroll
        for (int p = 0; p < 4; ++p) {
            s0 += partial4[p][row];
            s1 += partial4[4 + p][row];
            s2 += partial4[8 + p][row];
            s3 += partial4[12 + p][row];
        }
        part[(size_t)gf * B_SZ + rb + row] = (s0 + s1) + (s2 + s3);
    }
}

// ---- final: 1 row/thread, sum 32 gf-partials + bias + sigmoid ----
__global__ __launch_bounds__(256)
void nam_final(const float* __restrict__ part, const float* __restrict__ bias,
               float* __restrict__ out)
{
    int b = blockIdx.x * 256 + threadIdx.x;
    float s = bias[0];
    #pragma unroll
    for (int gf = 0; gf < 32; ++gf)
        s += part[(size_t)gf * B_SZ + b];
    float p = 1.0f / (1.0f + __expf(-s));
    ((float2*)out)[b] = make_float2(1.0f - p, p);
}

extern "C" void kernel_launch(void* const* d_in, const int* in_sizes, int n_in,
                              void* d_out, int out_size, void* d_ws, size_t ws_size,
                              hipStream_t stream)
{
    const float* x    = (const float*)d_in[0];
    const float* w1   = (const float*)d_in[1];
    const float* b1   = (const float*)d_in[2];
    const float* w2   = (const float*)d_in[3];
    const float* b2   = (const float*)d_in[4];
    const float* w3   = (const float*)d_in[5];
    const float* b3   = (const float*)d_in[6];
    const float* bias = (const float*)d_in[7];
    float* out = (float*)d_out;

    float* part = (float*)d_ws;   // part[32][B_SZ], 4MB

    nam_main<<<dim3(2048), dim3(256), 0, stream>>>(
        x, w1, b1, b2, w3, b3, w2, part);
    nam_final<<<dim3(B_SZ / 256), dim3(256), 0, stream>>>(part, bias, out);
}